// Round 2
// baseline (536.020 us; speedup 1.0000x reference)
//
#include <hip/hip_runtime.h>
#include <math.h>

// B=8, N=1024, D=256, H=4, hd=64, k=153
// Strategy: match the f64 numpy reference's top-k ranks exactly.
//   K1: src/tgt projections, f64 accumulate, stored as f64 in ws (32 MB).
//   K2: f64 adjacency accumulate, 64-bit radix top-k select on raw adj
//       (gelu is monotone for x>-0.75 and all top-153 values >> 0, so
//        topk(gelu(adj)) == topk(adj)); gelu applied in f32 at output only.
// ws layout (doubles): src_t [B,H,N,64] at 0 (16MB), tgt_t at +2097152 (16MB).

#define KSEL 153u

__device__ __forceinline__ float gelu_f32(float x) {
    return 0.5f * x * (1.0f + erff(x * 0.70710678118654752f));
}

// monotonic f64->u64 key: larger double => larger key
__device__ __forceinline__ unsigned long long d2key(double v) {
    unsigned long long u = (unsigned long long)__double_as_longlong(v);
    return (u >> 63) ? ~u : (u | 0x8000000000000000ull);
}

// ---------------- K1: projections, f64 accumulate, f64 store ----------------
// grid (128, 8): bx = 64-row m-tile of x[8192,256]; by<4 -> W_src cols (by&3)*64, else W_tgt.
__global__ __launch_bounds__(256) void k1_proj(const float* __restrict__ x,
                                               const float* __restrict__ Wsrc,
                                               const float* __restrict__ Wtgt,
                                               double* __restrict__ ws) {
    __shared__ float xs[32 * 68];   // xs[k][m]
    __shared__ float wsh[32 * 68];  // ws[k][c]
    const int t = threadIdx.x;
    const int bx = blockIdx.x;
    const int by = blockIdx.y;
    const int col0 = (by & 3) * 64;
    const float* __restrict__ W = (by < 4) ? Wsrc : Wtgt;
    double* __restrict__ outp = ws + ((by < 4) ? 0 : 2097152);

    double acc[4][4];
#pragma unroll
    for (int i = 0; i < 4; ++i)
#pragma unroll
        for (int j = 0; j < 4; ++j) acc[i][j] = 0.0;

    const int m_loc = (t & 15) * 4;
    const int c_loc = (t >> 4) * 4;

    for (int kt = 0; kt < 8; ++kt) {
        __syncthreads();
#pragma unroll
        for (int it = 0; it < 2; ++it) {
            int f4 = t + 256 * it;
            int m = f4 >> 3, k4 = f4 & 7;
            float4 v = *reinterpret_cast<const float4*>(&x[(bx * 64 + m) * 256 + kt * 32 + 4 * k4]);
            xs[(4 * k4 + 0) * 68 + m] = v.x;
            xs[(4 * k4 + 1) * 68 + m] = v.y;
            xs[(4 * k4 + 2) * 68 + m] = v.z;
            xs[(4 * k4 + 3) * 68 + m] = v.w;
        }
#pragma unroll
        for (int it = 0; it < 2; ++it) {
            int f4 = t + 256 * it;
            int k = f4 >> 4, c4 = f4 & 15;
            *reinterpret_cast<float4*>(&wsh[k * 68 + 4 * c4]) =
                *reinterpret_cast<const float4*>(&W[(kt * 32 + k) * 256 + col0 + 4 * c4]);
        }
        __syncthreads();
#pragma unroll
        for (int kk = 0; kk < 32; ++kk) {
            float4 a = *reinterpret_cast<const float4*>(&xs[kk * 68 + m_loc]);
            float4 b = *reinterpret_cast<const float4*>(&wsh[kk * 68 + c_loc]);
            double ad[4] = {a.x, a.y, a.z, a.w};
            double bd[4] = {b.x, b.y, b.z, b.w};
#pragma unroll
            for (int i = 0; i < 4; ++i)
#pragma unroll
                for (int j = 0; j < 4; ++j) acc[i][j] += ad[i] * bd[j];
        }
    }
    const int h = by & 3;
#pragma unroll
    for (int i = 0; i < 4; ++i) {
        int m = bx * 64 + m_loc + i;
        int b = m >> 10, n = m & 1023;
        size_t base = ((size_t)((b * 4 + h) * 1024 + n)) * 64 + c_loc;
        double2 v01, v23;
        v01.x = acc[i][0]; v01.y = acc[i][1];
        v23.x = acc[i][2]; v23.y = acc[i][3];
        *reinterpret_cast<double2*>(&outp[base]) = v01;
        *reinterpret_cast<double2*>(&outp[base + 2]) = v23;
    }
}

// ---------------- K2: f64 adj GEMM + exact f64 top-k + f32 gelu output ----------------
// grid 2048: bh = bx>>6 (0..31), itile = bx&63 -> 16-row tile. 256 thr = 4 waves.
// Wave wv owns rows 4*wv..4*wv+3. vals[i][c]: row r0+i, col = lane + 64*c (c=chunk).
__global__ __launch_bounds__(256) void k2_fused(const double* __restrict__ srcT,
                                                const double* __restrict__ tgtT,
                                                float* __restrict__ out) {
    __shared__ double2 tgt_s[32 * 64];  // [d2][j ^ (d2&7)]  (32 KB)
    __shared__ double2 src_s[16 * 32];  // [r][d2]           (8 KB)
    __shared__ unsigned hist[4][256];   // per-wave          (4 KB)

    const int t = threadIdx.x;
    const int lane = t & 63;
    const int wv = t >> 6;
    const int bh = blockIdx.x >> 6;
    const int itile = blockIdx.x & 63;
    const int row0 = itile * 16;
    const size_t srcBase = ((size_t)bh * 1024 + row0) * 64;
    const size_t tgtBase = (size_t)bh * 1024 * 64;

    // stage src rows (16 x 64 f64 = 512 double2, 2 per thread)
#pragma unroll
    for (int it = 0; it < 2; ++it) {
        int f = t + 256 * it;
        int d2 = f & 31, r = f >> 5;
        src_s[r * 32 + d2] = *reinterpret_cast<const double2*>(&srcT[srcBase + r * 64 + 2 * d2]);
    }

    double vals[4][16];
    const int r0 = 4 * wv;

    for (int c = 0; c < 16; ++c) {
        __syncthreads();  // prior chunk fully read (and src_s staged, for c==0)
        // stage tgt chunk (64 j x 32 d2 = 2048 double2, 8 per thread), coalesced global
#pragma unroll
        for (int it = 0; it < 8; ++it) {
            int f = t + 256 * it;
            int d2 = f & 31, j = f >> 5;
            double2 v = *reinterpret_cast<const double2*>(
                &tgtT[tgtBase + (size_t)(c * 64 + j) * 64 + 2 * d2]);
            tgt_s[d2 * 64 + (j ^ (d2 & 7))] = v;
        }
        __syncthreads();

        double acc0 = 0.0, acc1 = 0.0, acc2 = 0.0, acc3 = 0.0;
#pragma unroll
        for (int d2 = 0; d2 < 32; ++d2) {
            double2 b = tgt_s[d2 * 64 + (lane ^ (d2 & 7))];
            double2 a0 = src_s[(r0 + 0) * 32 + d2];
            double2 a1 = src_s[(r0 + 1) * 32 + d2];
            double2 a2 = src_s[(r0 + 2) * 32 + d2];
            double2 a3 = src_s[(r0 + 3) * 32 + d2];
            acc0 += a0.x * b.x + a0.y * b.y;
            acc1 += a1.x * b.x + a1.y * b.y;
            acc2 += a2.x * b.x + a2.y * b.y;
            acc3 += a3.x * b.x + a3.y * b.y;
        }
        vals[0][c] = acc0; vals[1][c] = acc1; vals[2][c] = acc2; vals[3][c] = acc3;
    }

#pragma unroll 1
    for (int ri = 0; ri < 4; ++ri) {
        unsigned long long keys[16];
#pragma unroll
        for (int m = 0; m < 16; ++m) keys[m] = d2key(vals[ri][m]);

        unsigned long long pref = 0ull, prefMask = 0ull;
        unsigned rk = KSEL;

#pragma unroll 1
        for (int p = 7; p >= 0; --p) {
            const int shift = 8 * p;
            *reinterpret_cast<uint4*>(&hist[wv][4 * lane]) = make_uint4(0u, 0u, 0u, 0u);
            __syncthreads();
#pragma unroll
            for (int m = 0; m < 16; ++m) {
                unsigned long long kk = keys[m];
                if ((kk & prefMask) == pref)
                    atomicAdd(&hist[wv][(unsigned)(kk >> shift) & 255u], 1u);
            }
            __syncthreads();
            unsigned h0 = hist[wv][4 * lane + 0], h1 = hist[wv][4 * lane + 1];
            unsigned h2 = hist[wv][4 * lane + 2], h3 = hist[wv][4 * lane + 3];
            unsigned S = h0 + h1 + h2 + h3;
            unsigned inc = S;  // suffix-inclusive sum over lanes >= lane
#pragma unroll
            for (int off = 1; off < 64; off <<= 1) {
                unsigned o = __shfl_down(inc, off, 64);
                inc = (lane + off < 64) ? (inc + o) : inc;
            }
            unsigned above = inc - S;
            bool found = (above < rk) && (rk <= inc);
            unsigned long long bal = __ballot(found);
            int L = __ffsll(bal) - 1;
            unsigned hh[4];
            hh[0] = __shfl(h0, L, 64);
            hh[1] = __shfl(h1, L, 64);
            hh[2] = __shfl(h2, L, 64);
            hh[3] = __shfl(h3, L, 64);
            unsigned cum = __shfl(above, L, 64);
            int bsel = -1;
#pragma unroll
            for (int q = 3; q >= 0; --q) {
                if (bsel < 0) {
                    if (rk <= cum + hh[q]) {
                        bsel = q;
                        rk = rk - cum;
                    } else {
                        cum += hh[q];
                    }
                }
            }
            pref |= ((unsigned long long)(4 * L + bsel)) << shift;
            prefMask |= (0xFFull << shift);
            __syncthreads();
        }

        // pref = exact f64 key of kth-largest; rk = count of tied values to keep (lowest col first)
        const size_t rowBase = ((size_t)bh * 1024 + row0 + r0 + ri) * 1024;
        unsigned run = 0;
#pragma unroll
        for (int m = 0; m < 16; ++m) {
            unsigned long long kk = keys[m];
            bool eq = (kk == pref);
            unsigned long long bal = __ballot(eq);
            unsigned below = (unsigned)__popcll(bal & ((1ull << lane) - 1ull));
            bool sel = (kk > pref) || (eq && ((run + below) < rk));
            run += (unsigned)__popcll(bal);
            float g = sel ? gelu_f32((float)vals[ri][m]) : 0.0f;
            out[rowBase + (unsigned)(lane + 64 * m)] = g;
        }
    }
}

extern "C" void kernel_launch(void* const* d_in, const int* in_sizes, int n_in,
                              void* d_out, int out_size, void* d_ws, size_t ws_size,
                              hipStream_t stream) {
    const float* x = (const float*)d_in[0];
    const float* Wsrc = (const float*)d_in[1];
    const float* Wtgt = (const float*)d_in[2];
    float* out = (float*)d_out;
    double* ws = (double*)d_ws;  // needs 32MB: src_t f64 (16MB) + tgt_t f64 (16MB)

    dim3 g1(128, 8);
    k1_proj<<<g1, 256, 0, stream>>>(x, Wsrc, Wtgt, ws);
    k2_fused<<<2048, 256, 0, stream>>>(ws, ws + 2097152, out);
}